// Round 1
// baseline (868.111 us; speedup 1.0000x reference)
//
#include <hip/hip_runtime.h>
#include <cmath>

// SoftmaxTreePrediction on MI355X.
// Output [N=16, C+1=2321, H=64, W=64] f32 is ~608 MB and almost all zeros:
// HBM-write-bound. Strategy: (1) nontemporal float4 zero-fill, (2) one thread
// per (n,h,w) lane runs the tiny stack-DFS (max depth 2 for this tree) and
// scatter-writes the sparse nonzero entries + max channel.

typedef float vfloat4 __attribute__((ext_vector_type(4)));

__global__ __launch_bounds__(256) void smt_zero_kernel(float* __restrict__ out,
                                                       long long n4, int rem) {
    long long i = (long long)blockIdx.x * blockDim.x + threadIdx.x;
    if (i < n4) {
        vfloat4 z = {0.f, 0.f, 0.f, 0.f};
        __builtin_nontemporal_store(z, (vfloat4*)out + i);
    } else if (i == n4) {
        // tail (out_size not divisible by 4 — defensive; not hit for this shape)
        for (int r = 0; r < rem; ++r) out[n4 * 4 + r] = 0.f;
    }
}

#define SMT_THRESHOLD 0.5f
#define SMT_STACK 16

__global__ __launch_bounds__(256) void smt_traverse_kernel(
    const float* __restrict__ conf,   // [N, C, inner]
    const float* __restrict__ obj,    // [N, inner]
    const int* __restrict__ go,       // group_offsets
    const int* __restrict__ gs,       // group_sizes
    const int* __restrict__ child,    // [C]
    const int* __restrict__ csize,    // [C]
    float* __restrict__ out,          // [N, C+1, inner] (pre-zeroed)
    int C, int inner_log2, int inner_mask, int total) {
    int lane = blockIdx.x * blockDim.x + threadIdx.x;
    if (lane >= total) return;
    int hw = lane & inner_mask;
    int inner = inner_mask + 1;
    long long nCinner = (long long)(lane - hw) * C;        // n*C*inner
    const float* cbase = conf + nCinner + hw;              // + ch*inner per channel
    float* obase = out + nCinner + (long long)(lane >> inner_log2) * inner + hw;
    // ^ n*(C+1)*inner + hw  ==  n*C*inner + n*inner + hw

    float o = obj[lane];

    // DFS stack (reference STACK=16; actual max depth 2 for this tree)
    int   sg[SMT_STACK];
    float sp[SMT_STACK];
    int   spa[SMT_STACK];
    sg[0] = 0; sp[0] = o; spa[0] = -1;
    int ptr = 1;
    float maxtop = 0.0f;

    while (ptr > 0) {
        ptr--;
        int g = sg[ptr];
        float pp = sp[ptr];
        int pa = spa[ptr];
        int off = go[g];
        int size = gs[g];
        // argmax (first-max tie-break, matching jnp.argmax)
        float best = -INFINITY;
        int bj = 0;
        for (int j = 0; j < size; ++j) {
            float v = cbase[(long long)(off + j) * inner];
            if (v > best) { best = v; bj = j; }
        }
        float p = pp * best;
        int amax = off + bj;
        int c = child[amax];
        int cs_n = csize[amax];
        if (p > SMT_THRESHOLD) {
            if (c < 0) {
                // leaf hit: top[amax] = p
                obase[(long long)amax * inner] = p;
                maxtop = fmaxf(maxtop, p);
            } else {
                int npush = cs_n + 1;
                for (int l = 0; l < npush; ++l) {
                    sg[ptr + l] = c + l;
                    sp[ptr + l] = p;
                    spa[ptr + l] = amax;
                }
                ptr += npush;
            }
        } else if (pa >= 0) {
            // pruned: top[pa] = parent path prob
            obase[(long long)pa * inner] = pp;
            maxtop = fmaxf(maxtop, pp);
        }
    }
    // append_max channel C (coalesced across lanes)
    obase[(long long)C * inner] = maxtop;
}

extern "C" void kernel_launch(void* const* d_in, const int* in_sizes, int n_in,
                              void* d_out, int out_size, void* d_ws, size_t ws_size,
                              hipStream_t stream) {
    const float* conf = (const float*)d_in[0];
    const float* obj  = (const float*)d_in[1];
    const int* go     = (const int*)d_in[2];
    const int* gs     = (const int*)d_in[3];
    const int* child  = (const int*)d_in[4];
    const int* csize  = (const int*)d_in[5];
    float* out = (float*)d_out;

    const int C = in_sizes[4];          // 2320 (node count == len(child))
    const int total = in_sizes[1];      // N * H * W = 65536
    const int inner = 64 * 64;          // H*W per reference
    const int inner_log2 = 12;
    const int inner_mask = inner - 1;

    // 1) zero-fill the output (harness poisons it to 0xAA before each call)
    long long n4 = (long long)out_size >> 2;
    int rem = out_size & 3;
    long long zthreads = n4 + (rem ? 1 : 0);
    int zblocks = (int)((zthreads + 255) / 256);
    smt_zero_kernel<<<zblocks, 256, 0, stream>>>(out, n4, rem);

    // 2) sparse DFS traversal + scatter
    int tblocks = (total + 255) / 256;
    smt_traverse_kernel<<<tblocks, 256, 0, stream>>>(
        conf, obj, go, gs, child, csize, out, C, inner_log2, inner_mask, total);
}